// Round 1
// baseline (196.048 us; speedup 1.0000x reference)
//
#include <hip/hip_runtime.h>

#define TILE_P 16      // pooled outputs per dim per block
#define TILE_C 32      // conv outputs per dim (= 2*TILE_P)
#define HALO 2
#define IN_TILE 36     // TILE_C + 2*HALO
#define IMG 224
#define OUT_DIM 112
#define NCH 16

__global__ __launch_bounds__(256, 4)
void conv_bn_relu_pool(const float* __restrict__ x,
                       const float* __restrict__ conv_w,
                       const float* __restrict__ conv_b,
                       const float* __restrict__ gamma,
                       const float* __restrict__ beta,
                       const float* __restrict__ run_mean,
                       const float* __restrict__ run_var,
                       float* __restrict__ out)
{
    __shared__ float smem[IN_TILE * IN_TILE];
    const int tid = threadIdx.x;
    const int b  = blockIdx.z;
    const int ty = blockIdx.y * TILE_C;   // conv-space tile origin y
    const int tx = blockIdx.x * TILE_C;

    const float* xb = x + (size_t)b * IMG * IMG;

    // Stage 36x36 input tile with zero padding at image borders.
    for (int i = tid; i < IN_TILE * IN_TILE; i += 256) {
        int r = i / IN_TILE, c = i - r * IN_TILE;
        int gy = ty - HALO + r, gx = tx - HALO + c;
        float v = 0.f;
        if ((unsigned)gy < IMG && (unsigned)gx < IMG) v = xb[gy * IMG + gx];
        smem[i] = v;
    }
    __syncthreads();

    const int px = tid & 15;      // pooled x within tile
    const int py = tid >> 4;      // pooled y within tile

    // Load this thread's 6x6 input patch into registers once; reused by all
    // 16 channels (16 * 100 = 1600 FMAs vs 36 LDS reads).
    float p[6][6];
    const int base = (py * 2) * IN_TILE + px * 2;
    #pragma unroll
    for (int r = 0; r < 6; ++r) {
        #pragma unroll
        for (int c = 0; c < 6; ++c) {
            p[r][c] = smem[base + r * IN_TILE + c];
        }
    }

    const int oy = blockIdx.y * TILE_P + py;
    const int ox = blockIdx.x * TILE_P + px;
    float* outb = out + (size_t)b * NCH * (OUT_DIM * OUT_DIM) + oy * OUT_DIM + ox;

    // Channel loop kept rolled (#pragma unroll 1) so only ~26 scalar weight
    // loads are live at a time (SGPR pressure); weights are wave-uniform so
    // the compiler emits s_load + v_fma with SGPR operand.
    #pragma unroll 1
    for (int ch = 0; ch < NCH; ++ch) {
        const float* w = conv_w + ch * 25;
        float a00 = 0.f, a01 = 0.f, a10 = 0.f, a11 = 0.f;
        #pragma unroll
        for (int dy = 0; dy < 5; ++dy) {
            #pragma unroll
            for (int dx = 0; dx < 5; ++dx) {
                const float wv = w[dy * 5 + dx];
                a00 = fmaf(wv, p[dy][dx],         a00);
                a01 = fmaf(wv, p[dy][dx + 1],     a01);
                a10 = fmaf(wv, p[dy + 1][dx],     a10);
                a11 = fmaf(wv, p[dy + 1][dx + 1], a11);
            }
        }
        // BN scale > 0 (gamma in [0.5,1.5], var+eps > 0) and ReLU monotone:
        // maxpool commutes with the affine + ReLU epilogue.
        float m = fmaxf(fmaxf(a00, a01), fmaxf(a10, a11));
        float s = gamma[ch] * rsqrtf(run_var[ch] + 1e-5f);
        float t = fmaf(-run_mean[ch], s, beta[ch]);   // beta - mean*s
        t = fmaf(conv_b[ch], s, t);                   // + conv_b*s (conv bias folded)
        float y = fmaxf(fmaf(m, s, t), 0.f);
        outb[ch * (OUT_DIM * OUT_DIM)] = y;
    }
}

extern "C" void kernel_launch(void* const* d_in, const int* in_sizes, int n_in,
                              void* d_out, int out_size, void* d_ws, size_t ws_size,
                              hipStream_t stream) {
    const float* x        = (const float*)d_in[0];
    const float* conv_w   = (const float*)d_in[1];
    const float* conv_b   = (const float*)d_in[2];
    const float* gamma    = (const float*)d_in[3];
    const float* beta     = (const float*)d_in[4];
    const float* run_mean = (const float*)d_in[5];
    const float* run_var  = (const float*)d_in[6];
    float* out = (float*)d_out;

    dim3 grid(IMG / TILE_C, IMG / TILE_C, 128);   // 7 x 7 x 128
    dim3 block(256);
    conv_bn_relu_pool<<<grid, block, 0, stream>>>(
        x, conv_w, conv_b, gamma, beta, run_mean, run_var, out);
}

// Round 3
// 174.975 us; speedup vs baseline: 1.1204x; 1.1204x over previous
//
#include <hip/hip_runtime.h>
#include <stdint.h>

#define TILE_P 16      // pooled outputs per dim per block
#define TILE_C 32      // conv outputs per dim (= 2*TILE_P)
#define HALO 2
#define IN_TILE 36     // TILE_C + 2*HALO
#define IMG 224
#define OUT_DIM 112
#define NCH 16

typedef __fp16 half2_t __attribute__((ext_vector_type(2)));

// d_ws layout (uint32 words):
//   [0 .. 31]   : 16 x float2 (scale, shift) per channel (shift folds conv_b, mean, beta)
//   [32 .. 351] : 16 ch x 5 rows x 4 half2 weight pairs: A=(w0,w1) B=(w2,w3) C=(w4,0) D=(0,w4)
#define WS_WPAIRS 32

__global__ void prep_kernel(const float* __restrict__ conv_w,
                            const float* __restrict__ conv_b,
                            const float* __restrict__ gamma,
                            const float* __restrict__ beta,
                            const float* __restrict__ run_mean,
                            const float* __restrict__ run_var,
                            uint32_t* __restrict__ ws)
{
    int ch = threadIdx.x;
    if (ch >= NCH) return;
    float s = gamma[ch] * rsqrtf(run_var[ch] + 1e-5f);
    float t = fmaf(s, conv_b[ch] - run_mean[ch], beta[ch]);
    float2* st = (float2*)ws;
    st[ch] = make_float2(s, t);

    uint32_t* wp = ws + WS_WPAIRS + ch * 20;
    const float* w = conv_w + ch * 25;
    for (int r = 0; r < 5; ++r) {
        half2_t A = __builtin_amdgcn_cvt_pkrtz(w[r*5+0], w[r*5+1]);
        half2_t B = __builtin_amdgcn_cvt_pkrtz(w[r*5+2], w[r*5+3]);
        half2_t C = __builtin_amdgcn_cvt_pkrtz(w[r*5+4], 0.f);
        half2_t D = __builtin_amdgcn_cvt_pkrtz(0.f, w[r*5+4]);
        wp[r*4+0] = __builtin_bit_cast(uint32_t, A);
        wp[r*4+1] = __builtin_bit_cast(uint32_t, B);
        wp[r*4+2] = __builtin_bit_cast(uint32_t, C);
        wp[r*4+3] = __builtin_bit_cast(uint32_t, D);
    }
}

__global__ __launch_bounds__(256, 4)
void conv_bn_relu_pool(const float* __restrict__ x,
                       const uint32_t* __restrict__ ws,
                       float* __restrict__ out)
{
    __shared__ float smem[IN_TILE * IN_TILE];
    const int tid = threadIdx.x;
    const int b  = blockIdx.z;
    const int ty = blockIdx.y * TILE_C;
    const int tx = blockIdx.x * TILE_C;

    const float* xb = x + (size_t)b * IMG * IMG;

    for (int i = tid; i < IN_TILE * IN_TILE; i += 256) {
        int r = i / IN_TILE, c = i - r * IN_TILE;
        int gy = ty - HALO + r, gx = tx - HALO + c;
        float v = 0.f;
        if ((unsigned)gy < IMG && (unsigned)gx < IMG) v = xb[gy * IMG + gx];
        smem[i] = v;
    }
    __syncthreads();

    const int px = tid & 15;
    const int py = tid >> 4;

    // 6x6 fp32 patch -> 6 rows x 5 sliding half2 pairs h2[r][s] = (p[r][s], p[r][s+1]).
    // cvt_pkrtz packs two f32->f16 in one VALU op. Full channel unroll below keeps
    // these CSE'd and register-resident (round-1 failure mode: unroll 1 caused LDS
    // re-reads per channel, VGPR_Count=24).
    const int base = (py * 2) * IN_TILE + px * 2;
    half2_t h2[6][5];
    #pragma unroll
    for (int r = 0; r < 6; ++r) {
        float p0 = smem[base + r * IN_TILE + 0];
        float p1 = smem[base + r * IN_TILE + 1];
        float p2 = smem[base + r * IN_TILE + 2];
        float p3 = smem[base + r * IN_TILE + 3];
        float p4 = smem[base + r * IN_TILE + 4];
        float p5 = smem[base + r * IN_TILE + 5];
        h2[r][0] = __builtin_amdgcn_cvt_pkrtz(p0, p1);
        h2[r][1] = __builtin_amdgcn_cvt_pkrtz(p1, p2);
        h2[r][2] = __builtin_amdgcn_cvt_pkrtz(p2, p3);
        h2[r][3] = __builtin_amdgcn_cvt_pkrtz(p3, p4);
        h2[r][4] = __builtin_amdgcn_cvt_pkrtz(p4, p5);
    }

    const int oy = blockIdx.y * TILE_P + py;
    const int ox = blockIdx.x * TILE_P + px;
    float* outb = out + (size_t)b * NCH * (OUT_DIM * OUT_DIM) + oy * OUT_DIM + ox;

    const float2* st = (const float2*)ws;

    #pragma unroll
    for (int ch = 0; ch < NCH; ++ch) {
        const uint32_t* wp = ws + WS_WPAIRS + ch * 20;   // wave-uniform -> s_load
        float a00 = 0.f, a01 = 0.f, a10 = 0.f, a11 = 0.f;
        #pragma unroll
        for (int r = 0; r < 5; ++r) {
            half2_t A = __builtin_bit_cast(half2_t, wp[r*4+0]);
            half2_t B = __builtin_bit_cast(half2_t, wp[r*4+1]);
            half2_t C = __builtin_bit_cast(half2_t, wp[r*4+2]);
            half2_t D = __builtin_bit_cast(half2_t, wp[r*4+3]);
            // a00: taps p[r][0..4];  a01: taps p[r][1..5] (tail via D=(0,w4) on (p4,p5))
            a00 = __builtin_amdgcn_fdot2(h2[r][0], A, a00, false);
            a00 = __builtin_amdgcn_fdot2(h2[r][2], B, a00, false);
            a00 = __builtin_amdgcn_fdot2(h2[r][4], C, a00, false);
            a01 = __builtin_amdgcn_fdot2(h2[r][1], A, a01, false);
            a01 = __builtin_amdgcn_fdot2(h2[r][3], B, a01, false);
            a01 = __builtin_amdgcn_fdot2(h2[r][4], D, a01, false);
            a10 = __builtin_amdgcn_fdot2(h2[r+1][0], A, a10, false);
            a10 = __builtin_amdgcn_fdot2(h2[r+1][2], B, a10, false);
            a10 = __builtin_amdgcn_fdot2(h2[r+1][4], C, a10, false);
            a11 = __builtin_amdgcn_fdot2(h2[r+1][1], A, a11, false);
            a11 = __builtin_amdgcn_fdot2(h2[r+1][3], B, a11, false);
            a11 = __builtin_amdgcn_fdot2(h2[r+1][4], D, a11, false);
        }
        // maxpool commutes with monotone BN(scale>0)+ReLU epilogue
        float m = fmaxf(fmaxf(a00, a01), fmaxf(a10, a11));
        float2 s_t = st[ch];
        float y = fmaxf(fmaf(m, s_t.x, s_t.y), 0.f);
        outb[ch * (OUT_DIM * OUT_DIM)] = y;
    }
}

extern "C" void kernel_launch(void* const* d_in, const int* in_sizes, int n_in,
                              void* d_out, int out_size, void* d_ws, size_t ws_size,
                              hipStream_t stream) {
    const float* x        = (const float*)d_in[0];
    const float* conv_w   = (const float*)d_in[1];
    const float* conv_b   = (const float*)d_in[2];
    const float* gamma    = (const float*)d_in[3];
    const float* beta     = (const float*)d_in[4];
    const float* run_mean = (const float*)d_in[5];
    const float* run_var  = (const float*)d_in[6];
    float* out = (float*)d_out;
    uint32_t* ws = (uint32_t*)d_ws;

    prep_kernel<<<1, 64, 0, stream>>>(conv_w, conv_b, gamma, beta, run_mean, run_var, ws);

    dim3 grid(IMG / TILE_C, IMG / TILE_C, 128);   // 7 x 7 x 128
    dim3 block(256);
    conv_bn_relu_pool<<<grid, block, 0, stream>>>(x, ws, out);
}

// Round 4
// 173.411 us; speedup vs baseline: 1.1305x; 1.0090x over previous
//
#include <hip/hip_runtime.h>
#include <stdint.h>

#define TILE_P 16      // pooled outputs per dim per block
#define TILE_C 32      // conv outputs per dim (= 2*TILE_P)
#define HALO 2
#define IN_TILE 36     // TILE_C + 2*HALO
#define IMG 224
#define OUT_DIM 112
#define NCH 16
#define PAIR_STRIDE 40 // pair-row stride in half2 units (160B, keeps b64 alignment)

typedef __fp16 half2_t __attribute__((ext_vector_type(2)));

// d_ws layout (uint32 words):
//   [0 .. 31]   : 16 x float2 (scale, shift) per channel (folds conv_b, mean, beta)
//   [32 .. 351] : 16 ch x 5 rows x 4 half2 weight pairs: A=(w0,w1) B=(w2,w3) C=(w4,0) D=(0,w4)
#define WS_WPAIRS 32

__global__ void prep_kernel(const float* __restrict__ conv_w,
                            const float* __restrict__ conv_b,
                            const float* __restrict__ gamma,
                            const float* __restrict__ beta,
                            const float* __restrict__ run_mean,
                            const float* __restrict__ run_var,
                            uint32_t* __restrict__ ws)
{
    int ch = threadIdx.x;
    if (ch >= NCH) return;
    float s = gamma[ch] * rsqrtf(run_var[ch] + 1e-5f);
    float t = fmaf(s, conv_b[ch] - run_mean[ch], beta[ch]);
    float2* st = (float2*)ws;
    st[ch] = make_float2(s, t);

    uint32_t* wp = ws + WS_WPAIRS + ch * 20;
    const float* w = conv_w + ch * 25;
    for (int r = 0; r < 5; ++r) {
        half2_t A = __builtin_amdgcn_cvt_pkrtz(w[r*5+0], w[r*5+1]);
        half2_t B = __builtin_amdgcn_cvt_pkrtz(w[r*5+2], w[r*5+3]);
        half2_t C = __builtin_amdgcn_cvt_pkrtz(w[r*5+4], 0.f);
        half2_t D = __builtin_amdgcn_cvt_pkrtz(0.f, w[r*5+4]);
        wp[r*4+0] = __builtin_bit_cast(uint32_t, A);
        wp[r*4+1] = __builtin_bit_cast(uint32_t, B);
        wp[r*4+2] = __builtin_bit_cast(uint32_t, C);
        wp[r*4+3] = __builtin_bit_cast(uint32_t, D);
    }
}

__device__ __forceinline__ half2_t ld_pair(const uint32_t* p) {
    return __builtin_bit_cast(half2_t, *p);
}

__global__ __launch_bounds__(256)
void conv_bn_relu_pool(const float* __restrict__ x,
                       const uint32_t* __restrict__ ws,
                       float* __restrict__ out)
{
    __shared__ float T[IN_TILE * IN_TILE];          // fp32 input tile
    __shared__ uint32_t P[IN_TILE * PAIR_STRIDE];   // sliding half2 pairs (T[r][c],T[r][c+1])

    const int tid = threadIdx.x;
    const int b  = blockIdx.z;
    const int ty = blockIdx.y * TILE_C;
    const int tx = blockIdx.x * TILE_C;

    const float* xb = x + (size_t)b * IMG * IMG;

    // Pass 1: stage 36x36 fp32 tile (zero-padded halo).
    for (int i = tid; i < IN_TILE * IN_TILE; i += 256) {
        int r = i / IN_TILE, c = i - r * IN_TILE;
        int gy = ty - HALO + r, gx = tx - HALO + c;
        float v = 0.f;
        if ((unsigned)gy < IMG && (unsigned)gx < IMG) v = xb[gy * IMG + gx];
        T[i] = v;
    }
    __syncthreads();

    // Pass 2: pack sliding pairs P[r][c] = (T[r][c], T[r][c+1]) as half2.
    // Hot loop then feeds dot2 straight from LDS — nothing left to rematerialize.
    for (int i = tid; i < IN_TILE * (IN_TILE - 1); i += 256) {
        int r = i / (IN_TILE - 1), c = i - r * (IN_TILE - 1);
        half2_t h = __builtin_amdgcn_cvt_pkrtz(T[r * IN_TILE + c], T[r * IN_TILE + c + 1]);
        P[r * PAIR_STRIDE + c] = __builtin_bit_cast(uint32_t, h);
    }
    __syncthreads();

    const int px = tid & 15;
    const int py = tid >> 4;
    const uint32_t* prow = P + (2 * py) * PAIR_STRIDE + 2 * px;

    const int oy = blockIdx.y * TILE_P + py;
    const int ox = blockIdx.x * TILE_P + px;
    float* outb = out + (size_t)b * NCH * (OUT_DIM * OUT_DIM) + oy * OUT_DIM + ox;

    const float2* st = (const float2*)ws;

    // 4 channels per group, group loop NOT unrolled: per-group live state is just
    // 16 loop-carried accumulators (unsinkable) + transient pair regs. Weights for
    // the group = 80 uniform dwords -> s_load. LDS pairs re-read once per group
    // (4x redundancy) by design — cheaper than fighting the register allocator.
    #pragma unroll 1
    for (int g = 0; g < 4; ++g) {
        const uint32_t* wp = ws + WS_WPAIRS + g * 80;
        float acc[4][4];
        #pragma unroll
        for (int i = 0; i < 4; ++i)
            #pragma unroll
            for (int j = 0; j < 4; ++j) acc[i][j] = 0.f;

        #pragma unroll
        for (int r = 0; r < 5; ++r) {
            const uint32_t* p0 = prow + r * PAIR_STRIDE;        // row for a00/a01
            const uint32_t* p1 = p0 + PAIR_STRIDE;              // row for a10/a11
            half2_t q00 = ld_pair(p0 + 0), q01 = ld_pair(p0 + 1);
            half2_t q02 = ld_pair(p0 + 2), q03 = ld_pair(p0 + 3);
            half2_t q04 = ld_pair(p0 + 4);
            half2_t q10 = ld_pair(p1 + 0), q11 = ld_pair(p1 + 1);
            half2_t q12 = ld_pair(p1 + 2), q13 = ld_pair(p1 + 3);
            half2_t q14 = ld_pair(p1 + 4);
            #pragma unroll
            for (int i = 0; i < 4; ++i) {
                half2_t A = __builtin_bit_cast(half2_t, wp[i*20 + r*4 + 0]);
                half2_t B = __builtin_bit_cast(half2_t, wp[i*20 + r*4 + 1]);
                half2_t C = __builtin_bit_cast(half2_t, wp[i*20 + r*4 + 2]);
                half2_t D = __builtin_bit_cast(half2_t, wp[i*20 + r*4 + 3]);
                acc[i][0] = __builtin_amdgcn_fdot2(q00, A,
                            __builtin_amdgcn_fdot2(q02, B,
                            __builtin_amdgcn_fdot2(q04, C, acc[i][0], false), false), false);
                acc[i][1] = __builtin_amdgcn_fdot2(q01, A,
                            __builtin_amdgcn_fdot2(q03, B,
                            __builtin_amdgcn_fdot2(q04, D, acc[i][1], false), false), false);
                acc[i][2] = __builtin_amdgcn_fdot2(q10, A,
                            __builtin_amdgcn_fdot2(q12, B,
                            __builtin_amdgcn_fdot2(q14, C, acc[i][2], false), false), false);
                acc[i][3] = __builtin_amdgcn_fdot2(q11, A,
                            __builtin_amdgcn_fdot2(q13, B,
                            __builtin_amdgcn_fdot2(q14, D, acc[i][3], false), false), false);
            }
        }

        // maxpool commutes with monotone BN(scale>0)+ReLU epilogue
        #pragma unroll
        for (int i = 0; i < 4; ++i) {
            int ch = g * 4 + i;
            float m = fmaxf(fmaxf(acc[i][0], acc[i][1]), fmaxf(acc[i][2], acc[i][3]));
            float2 s_t = st[ch];
            float y = fmaxf(fmaf(m, s_t.x, s_t.y), 0.f);
            outb[ch * (OUT_DIM * OUT_DIM)] = y;
        }
    }
}

extern "C" void kernel_launch(void* const* d_in, const int* in_sizes, int n_in,
                              void* d_out, int out_size, void* d_ws, size_t ws_size,
                              hipStream_t stream) {
    const float* x        = (const float*)d_in[0];
    const float* conv_w   = (const float*)d_in[1];
    const float* conv_b   = (const float*)d_in[2];
    const float* gamma    = (const float*)d_in[3];
    const float* beta     = (const float*)d_in[4];
    const float* run_mean = (const float*)d_in[5];
    const float* run_var  = (const float*)d_in[6];
    float* out = (float*)d_out;
    uint32_t* ws = (uint32_t*)d_ws;

    prep_kernel<<<1, 64, 0, stream>>>(conv_w, conv_b, gamma, beta, run_mean, run_var, ws);

    dim3 grid(IMG / TILE_C, IMG / TILE_C, 128);   // 7 x 7 x 128
    dim3 block(256);
    conv_bn_relu_pool<<<grid, block, 0, stream>>>(x, ws, out);
}